// Round 5
// baseline (1878.727 us; speedup 1.0000x reference)
//
#include <hip/hip_runtime.h>

constexpr int NLAYER = 6;
constexpr int SEQ    = 128;
constexpr int NVOCAB = 32000;
constexpr unsigned NB = 256;          // grid size; 1 block/CU, co-resident

// ---------------- workspace layout (float offsets) ----------------
constexpr size_t O_H    = 0;                           // [128][256] residual h
constexpr size_t O_HN   = O_H    + (size_t)SEQ*256;    // [128][256] LN1(h) for current layer
constexpr size_t O_XZ   = O_HN   + (size_t)SEQ*256;    // [128][1024]
constexpr size_t O_U    = O_XZ   + (size_t)SEQ*1024;   // [128][512]
constexpr size_t O_BC   = O_U    + (size_t)SEQ*512;    // [128][32]  (B cols 0..15, C cols 16..31)
constexpr size_t O_DT   = O_BC   + (size_t)SEQ*32;     // [128][512]
constexpr size_t O_YG   = O_DT   + (size_t)SEQ*512;    // [128][512]
constexpr size_t O_AH   = O_YG   + (size_t)SEQ*512;    // [128][256] LNf output
constexpr size_t O_BAR  = O_AH   + (size_t)SEQ*256;    // 4 uints (memset to 0 pre-launch)

__device__ __forceinline__ float wsum(float p) {
    #pragma unroll
    for (int m = 1; m < 64; m <<= 1) p += __shfl_xor(p, m);
    return p;
}
__device__ __forceinline__ float dot4(float4 a, float4 b) {
    return a.x*b.x + a.y*b.y + a.z*b.z + a.w*b.w;
}

// grid barrier: relaxed spin (no per-poll cache maintenance), one fence each side
__device__ __forceinline__ void gbar(unsigned* bar) {
    __threadfence();                      // release: drain + make writes visible device-wide
    __syncthreads();
    if (threadIdx.x == 0) {
        unsigned gen = __hip_atomic_load(&bar[1], __ATOMIC_RELAXED, __HIP_MEMORY_SCOPE_AGENT);
        unsigned arr = __hip_atomic_fetch_add(&bar[0], 1u, __ATOMIC_RELAXED, __HIP_MEMORY_SCOPE_AGENT);
        if (arr == NB - 1u) {
            __hip_atomic_store(&bar[0], 0u, __ATOMIC_RELAXED, __HIP_MEMORY_SCOPE_AGENT);
            __hip_atomic_store(&bar[1], gen + 1u, __ATOMIC_RELAXED, __HIP_MEMORY_SCOPE_AGENT);
        } else {
            while (__hip_atomic_load(&bar[1], __ATOMIC_RELAXED, __HIP_MEMORY_SCOPE_AGENT) == gen)
                __builtin_amdgcn_s_sleep(2);
        }
    }
    __syncthreads();
    __threadfence();                      // acquire: invalidate caches before reading others' data
}

// wave-0 LN stats over a 256-float LDS row -> red[0]=mean, red[1]=rstd
__device__ __forceinline__ void ln_stats(const float* shm, float* red) {
    if (threadIdx.x < 64) {
        int lane = threadIdx.x;
        float x0 = shm[lane], x1 = shm[lane+64], x2 = shm[lane+128], x3 = shm[lane+192];
        float s = wsum(x0 + x1 + x2 + x3);
        float mean = s * (1.0f/256.0f);
        float d0 = x0-mean, d1 = x1-mean, d2 = x2-mean, d3 = x3-mean;
        float v = wsum(d0*d0 + d1*d1 + d2*d2 + d3*d3);
        if (lane == 0) { red[0] = mean; red[1] = rsqrtf(v*(1.0f/256.0f) + 1e-5f); }
    }
}

__global__ __launch_bounds__(256) void fused_kernel(
    const int* __restrict__ x, const float* __restrict__ emb,
    const float* __restrict__ n1w, const float* __restrict__ n1b,
    const float* __restrict__ n2w, const float* __restrict__ n2b,
    const float* __restrict__ ipw, const float* __restrict__ cw, const float* __restrict__ cb,
    const float* __restrict__ xpw, const float* __restrict__ dpw, const float* __restrict__ dpb,
    const float* __restrict__ alog, const float* __restrict__ dsk,
    const float* __restrict__ opw, const float* __restrict__ aiw, const float* __restrict__ aib,
    const float* __restrict__ aow, const float* __restrict__ aob,
    const float* __restrict__ nfw, const float* __restrict__ nfb,
    const float* __restrict__ hb,
    float* __restrict__ ws, float* __restrict__ out)
{
    __shared__ float smem[8448];   // 33 KB, aliased per phase

    float* hg   = ws + O_H;
    float* hn   = ws + O_HN;
    float* xz   = ws + O_XZ;
    float* ug   = ws + O_U;
    float* bc   = ws + O_BC;
    float* dtg  = ws + O_DT;
    float* yg   = ws + O_YG;
    float* AH   = ws + O_AH;
    unsigned* bar = (unsigned*)(ws + O_BAR);

    int bid  = blockIdx.x;
    int tid  = threadIdx.x;
    int lane = tid & 63;
    int wv   = tid >> 6;

    // ---- P0: embed + LN1 layer0 (blocks 0..127) ----
    if (bid < SEQ) {
        float* sh  = smem;
        float* red = smem + 768;
        int r = bid;
        float e = emb[(size_t)x[r]*256 + tid];
        hg[r*256 + tid] = e;
        sh[tid] = e;
        __syncthreads();
        ln_stats(sh, red);
        __syncthreads();
        hn[r*256 + tid] = (e - red[0])*red[1]*n1w[tid] + n1b[tid];
    }
    gbar(bar);

    for (int l = 0; l < NLAYER; ++l) {
        const float* ipw_l = ipw + (size_t)l*1024*256;
        const float* cw_l  = cw  + (size_t)l*512*4;
        const float* cb_l  = cb  + (size_t)l*512;
        const float* xpw_l = xpw + (size_t)l*48*512;
        const float* dpw_l = dpw + (size_t)l*512*16;
        const float* dpb_l = dpb + (size_t)l*512;
        const float* alog_l= alog+ (size_t)l*512*16;
        const float* dsk_l = dsk + (size_t)l*512;
        const float* opw_l = opw + (size_t)l*256*512;
        const float* aivw_l= aiw + (size_t)l*768*256 + (size_t)512*256;
        const float* aivb_l= aib + (size_t)l*768 + 512;
        const float* aow_l = aow + (size_t)l*256*256;
        const float* aob_l = aob + (size_t)l*256;

        // ---- P1: in_proj tiled GEMM  xz(128,1024) = hn(128,256) @ ipw^T ----
        // 256 blocks: 16 col-tiles (64) x 16 row-tiles (8). Outer-product from LDS.
        {
            float* sA = smem;            // [8][256]
            float* sW = smem + 2048;     // [32][66] transposed chunk
            int ct = bid & 15, rt = bid >> 4;
            int c0 = ct*64, r0 = rt*8;
            #pragma unroll
            for (int j = 0; j < 2; ++j) {
                int f4 = j*256 + tid;
                int row = f4 >> 6, k4 = f4 & 63;
                *(float4*)&sA[row*256 + k4*4] = *(const float4*)&hn[(size_t)(r0+row)*256 + k4*4];
            }
            int r8 = tid >> 5;
            int cp = (tid & 31)*2;
            float acc0 = 0.f, acc1 = 0.f;
            for (int kc = 0; kc < 256; kc += 32) {
                __syncthreads();
                #pragma unroll
                for (int j = 0; j < 2; ++j) {
                    int f4 = j*256 + tid;
                    int c = f4 >> 3, k4 = f4 & 7;
                    float4 w = *(const float4*)&ipw_l[(size_t)(c0+c)*256 + kc + k4*4];
                    int kk = k4*4;
                    sW[(kk+0)*66 + c] = w.x; sW[(kk+1)*66 + c] = w.y;
                    sW[(kk+2)*66 + c] = w.z; sW[(kk+3)*66 + c] = w.w;
                }
                __syncthreads();
                #pragma unroll
                for (int k = 0; k < 32; ++k) {
                    float a = sA[r8*256 + kc + k];
                    float2 w = *(const float2*)&sW[k*66 + cp];
                    acc0 += a*w.x; acc1 += a*w.y;
                }
            }
            float2 o; o.x = acc0; o.y = acc1;
            *(float2*)&xz[(size_t)(r0+r8)*1024 + c0 + cp] = o;
        }
        gbar(bar);

        // ---- P2: conv+silu -> u ; x_proj -> B,C ; dt_proj+softplus -> dt  (blocks 0..127) ----
        if (bid < SEQ) {
            float* su = smem;            // [512]
            float* sx = smem + 512;      // [48]
            int r = bid;
            #pragma unroll
            for (int half = 0; half < 2; ++half) {
                int c = half*256 + tid;
                float4 cw4 = *(const float4*)&cw_l[c*4];
                float xv[4];
                #pragma unroll
                for (int k = 0; k < 4; ++k) {
                    int gt = r - 3 + k;
                    xv[k] = (gt >= 0) ? xz[(size_t)gt*1024 + c] : 0.0f;
                }
                float acc = cb_l[c] + xv[0]*cw4.x + xv[1]*cw4.y + xv[2]*cw4.z + xv[3]*cw4.w;
                float sg = acc / (1.0f + __expf(-acc));
                su[c] = sg;
                ug[r*512 + c] = sg;
            }
            __syncthreads();
            {
                float4 a0 = *(const float4*)&su[lane*4];
                float4 a1 = *(const float4*)&su[256 + lane*4];
                #pragma unroll
                for (int ci = 0; ci < 12; ci += 4) {
                    float p[4];
                    #pragma unroll
                    for (int j = 0; j < 4; ++j) {
                        int c = wv*12 + ci + j;
                        float4 q0 = *(const float4*)&xpw_l[(size_t)c*512 + lane*4];
                        float4 q1 = *(const float4*)&xpw_l[(size_t)c*512 + 256 + lane*4];
                        p[j] = dot4(a0,q0) + dot4(a1,q1);
                    }
                    #pragma unroll
                    for (int m = 1; m < 64; m <<= 1) {
                        #pragma unroll
                        for (int j = 0; j < 4; ++j) p[j] += __shfl_xor(p[j], m);
                    }
                    if (lane == 0) {
                        #pragma unroll
                        for (int j = 0; j < 4; ++j) {
                            int c = wv*12 + ci + j;
                            sx[c] = p[j];
                            if (c >= 16) bc[r*32 + (c - 16)] = p[j];
                        }
                    }
                }
            }
            __syncthreads();
            #pragma unroll
            for (int half = 0; half < 2; ++half) {
                int c = half*256 + tid;
                float acc = dpb_l[c];
                const float4* dp4 = (const float4*)&dpw_l[c*16];
                #pragma unroll
                for (int j4 = 0; j4 < 4; ++j4) {
                    float4 dq = dp4[j4];
                    acc += sx[j4*4+0]*dq.x + sx[j4*4+1]*dq.y
                         + sx[j4*4+2]*dq.z + sx[j4*4+3]*dq.w;
                }
                dtg[r*512 + c] = fmaxf(acc, 0.0f) + log1pf(__expf(-fabsf(acc)));
            }
        }
        gbar(bar);

        // ---- P3: selective scan + skip + gate -> yg (blocks 0..31, 16 channels each) ----
        if (bid < 32) {
            float* sdt = smem;        float* su2 = smem + 128;
            float* sz2 = smem + 256;  float* sB  = smem + 384;  float* sC = smem + 512;
            int s  = tid & 15, dl = tid >> 4;
            int d0 = bid * 16;
            int d  = d0 + dl;
            float a_ds = -__expf(alog_l[d*16 + s]);
            float dskv = dsk_l[d];
            float hst = 0.0f;
            for (int t0 = 0; t0 < SEQ; t0 += 8) {
                __syncthreads();
                if (tid < 128) {
                    int tt = tid >> 4, j = tid & 15;
                    int t = t0 + tt;
                    sdt[tt*16+j] = dtg[t*512 + d0 + j];
                    su2[tt*16+j] = ug [t*512 + d0 + j];
                    sz2[tt*16+j] = xz [(size_t)t*1024 + 512 + d0 + j];
                } else {
                    int q = tid - 128;
                    int tt = q >> 4, j = q & 15;
                    int t = t0 + tt;
                    sB[tt*16+j] = bc[t*32 + j];
                    sC[tt*16+j] = bc[t*32 + 16 + j];
                }
                __syncthreads();
                #pragma unroll
                for (int tt = 0; tt < 8; ++tt) {
                    float dtv = sdt[tt*16+dl];
                    float uv  = su2[tt*16+dl];
                    hst = __expf(dtv * a_ds) * hst + dtv * uv * sB[tt*16+s];
                    float p = hst * sC[tt*16+s];
                    p += __shfl_xor(p, 1);
                    p += __shfl_xor(p, 2);
                    p += __shfl_xor(p, 4);
                    p += __shfl_xor(p, 8);
                    if (s == 0) {
                        float zv = sz2[tt*16+dl];
                        float y = p + uv * dskv;
                        yg[(t0+tt)*512 + d] = y * (zv / (1.0f + __expf(-zv)));
                    }
                }
            }
        }
        gbar(bar);

        // ---- P45: out_proj+resid ; LN2 ; v ; attn_out+resid ; next LN (blocks 0..127) ----
        if (bid < SEQ) {
            float* sh  = smem;         // [256]
            float* sv  = smem + 256;   // [256]
            float* sX  = smem + 512;   // [256]
            float* red = smem + 768;   // [2]
            int r = bid;
            sh[tid] = hg[r*256 + tid];
            __syncthreads();
            {   // out_proj GEMV (K=512), 64 cols/wave, unroll 4
                float4 y0 = *(const float4*)&yg[(size_t)r*512 + lane*4];
                float4 y1 = *(const float4*)&yg[(size_t)r*512 + 256 + lane*4];
                #pragma unroll
                for (int ci = 0; ci < 64; ci += 4) {
                    float p[4];
                    #pragma unroll
                    for (int j = 0; j < 4; ++j) {
                        int c = wv*64 + ci + j;
                        float4 q0 = *(const float4*)&opw_l[(size_t)c*512 + lane*4];
                        float4 q1 = *(const float4*)&opw_l[(size_t)c*512 + 256 + lane*4];
                        p[j] = dot4(y0,q0) + dot4(y1,q1);
                    }
                    #pragma unroll
                    for (int m = 1; m < 64; m <<= 1) {
                        #pragma unroll
                        for (int j = 0; j < 4; ++j) p[j] += __shfl_xor(p[j], m);
                    }
                    if (lane == 0) {
                        #pragma unroll
                        for (int j = 0; j < 4; ++j) sh[wv*64 + ci + j] += p[j];
                    }
                }
            }
            __syncthreads();
            ln_stats(sh, red);
            __syncthreads();
            sv[tid] = (sh[tid] - red[0])*red[1]*n2w[l*256 + tid] + n2b[l*256 + tid];
            __syncthreads();
            {   // v-proj GEMV (K=256)
                float4 a = *(const float4*)&sv[lane*4];
                #pragma unroll
                for (int ci = 0; ci < 64; ci += 4) {
                    float p[4];
                    #pragma unroll
                    for (int j = 0; j < 4; ++j) {
                        int c = wv*64 + ci + j;
                        float4 q = *(const float4*)&aivw_l[(size_t)c*256 + lane*4];
                        p[j] = dot4(a, q);
                    }
                    #pragma unroll
                    for (int m = 1; m < 64; m <<= 1) {
                        #pragma unroll
                        for (int j = 0; j < 4; ++j) p[j] += __shfl_xor(p[j], m);
                    }
                    if (lane == 0) {
                        #pragma unroll
                        for (int j = 0; j < 4; ++j) {
                            int c = wv*64 + ci + j;
                            sX[c] = p[j] + aivb_l[c];
                        }
                    }
                }
            }
            __syncthreads();
            {   // attn_out GEMV (K=256) + resid
                float4 a = *(const float4*)&sX[lane*4];
                #pragma unroll
                for (int ci = 0; ci < 64; ci += 4) {
                    float p[4];
                    #pragma unroll
                    for (int j = 0; j < 4; ++j) {
                        int c = wv*64 + ci + j;
                        float4 q = *(const float4*)&aow_l[(size_t)c*256 + lane*4];
                        p[j] = dot4(a, q);
                    }
                    #pragma unroll
                    for (int m = 1; m < 64; m <<= 1) {
                        #pragma unroll
                        for (int j = 0; j < 4; ++j) p[j] += __shfl_xor(p[j], m);
                    }
                    if (lane == 0) {
                        #pragma unroll
                        for (int j = 0; j < 4; ++j) {
                            int c = wv*64 + ci + j;
                            sh[c] += p[j] + aob_l[c];
                        }
                    }
                }
            }
            __syncthreads();
            hg[r*256 + tid] = sh[tid];
            ln_stats(sh, red);
            __syncthreads();
            if (l < NLAYER-1)
                hn[r*256 + tid] = (sh[tid] - red[0])*red[1]*n1w[(l+1)*256 + tid] + n1b[(l+1)*256 + tid];
            else
                AH[r*256 + tid] = (sh[tid] - red[0])*red[1]*nfw[tid] + nfb[tid];
        }
        gbar(bar);
    }

    // ---- head: out(128,32000) = AH @ emb^T + hb ; 128-col tiles, pad-129 LDS ----
    if (bid < NVOCAB/128) {
        float* sA = smem;              // [32*129]
        float* sW = smem + 32*129;     // [32*129]
        int c0 = bid * 128;
        int rr = tid >> 1;
        int kj = (tid & 1) * 16;
        int r4 = (tid >> 4) * 4;
        int c4 = (tid & 15) * 4;
        float acc[8][8] = {};

        for (int kc = 0; kc < 256; kc += 32) {
            __syncthreads();
            #pragma unroll
            for (int i = 0; i < 4; ++i) {
                float4 a = *(const float4*)&AH[(size_t)rr*256 + kc + kj + i*4];
                sA[(kj+i*4+0)*129 + rr] = a.x;
                sA[(kj+i*4+1)*129 + rr] = a.y;
                sA[(kj+i*4+2)*129 + rr] = a.z;
                sA[(kj+i*4+3)*129 + rr] = a.w;
                float4 w = *(const float4*)&emb[(size_t)(c0+rr)*256 + kc + kj + i*4];
                sW[(kj+i*4+0)*129 + rr] = w.x;
                sW[(kj+i*4+1)*129 + rr] = w.y;
                sW[(kj+i*4+2)*129 + rr] = w.z;
                sW[(kj+i*4+3)*129 + rr] = w.w;
            }
            __syncthreads();
            #pragma unroll
            for (int k = 0; k < 32; ++k) {
                float4 a0 = *(const float4*)&sA[k*129 + r4];
                float4 a1 = *(const float4*)&sA[k*129 + 64 + r4];
                float4 b0 = *(const float4*)&sW[k*129 + c4];
                float4 b1 = *(const float4*)&sW[k*129 + 64 + c4];
                float av[8] = {a0.x,a0.y,a0.z,a0.w, a1.x,a1.y,a1.z,a1.w};
                float bv[8] = {b0.x,b0.y,b0.z,b0.w, b1.x,b1.y,b1.z,b1.w};
                #pragma unroll
                for (int i = 0; i < 8; ++i)
                    #pragma unroll
                    for (int j = 0; j < 8; ++j)
                        acc[i][j] += av[i]*bv[j];
            }
        }
        #pragma unroll
        for (int i = 0; i < 8; ++i) {
            int r = (i < 4) ? (r4 + i) : (64 + r4 + i - 4);
            #pragma unroll
            for (int jh = 0; jh < 2; ++jh) {
                int c = c0 + jh*64 + c4;
                float4 h4 = *(const float4*)&hb[c];
                float4 o;
                o.x = acc[i][jh*4+0] + h4.x;
                o.y = acc[i][jh*4+1] + h4.y;
                o.z = acc[i][jh*4+2] + h4.z;
                o.w = acc[i][jh*4+3] + h4.w;
                *(float4*)&out[(size_t)r*NVOCAB + c] = o;
            }
        }
    }
}

// ---------------- launch ----------------
extern "C" void kernel_launch(void* const* d_in, const int* in_sizes, int n_in,
                              void* d_out, int out_size, void* d_ws, size_t ws_size,
                              hipStream_t stream)
{
    const int*   xin = (const int*)d_in[0];
    const float* emb = (const float*)d_in[1];
    const float* n1w = (const float*)d_in[2];
    const float* n1b = (const float*)d_in[3];
    const float* n2w = (const float*)d_in[4];
    const float* n2b = (const float*)d_in[5];
    const float* ipw = (const float*)d_in[6];
    const float* cw  = (const float*)d_in[7];
    const float* cb  = (const float*)d_in[8];
    const float* xpw = (const float*)d_in[9];
    const float* dpw = (const float*)d_in[10];
    const float* dpb = (const float*)d_in[11];
    const float* alog= (const float*)d_in[12];
    const float* dsk = (const float*)d_in[13];
    const float* opw = (const float*)d_in[14];
    const float* aiw = (const float*)d_in[15];
    const float* aib = (const float*)d_in[16];
    const float* aow = (const float*)d_in[17];
    const float* aob = (const float*)d_in[18];
    const float* nfw = (const float*)d_in[19];
    const float* nfb = (const float*)d_in[20];
    const float* hb  = (const float*)d_in[21];
    float* ws  = (float*)d_ws;
    float* out = (float*)d_out;

    hipMemsetAsync((char*)d_ws + O_BAR*sizeof(float), 0, 16, stream);
    fused_kernel<<<NB, 256, 0, stream>>>(xin, emb, n1w, n1b, n2w, n2b, ipw, cw, cb,
                                         xpw, dpw, dpb, alog, dsk, opw, aiw, aib,
                                         aow, aob, nfw, nfb, hb, ws, out);
}

// Round 6
// 820.693 us; speedup vs baseline: 2.2892x; 2.2892x over previous
//
#include <hip/hip_runtime.h>

constexpr int SEQ    = 128;
constexpr int NVOCAB = 32000;

// ---------------- workspace layout (float offsets) ----------------
constexpr size_t O_HA = 0;                          // [128][256]
constexpr size_t O_HB = O_HA + (size_t)SEQ*256;     // [128][256]
constexpr size_t O_U  = O_HB + (size_t)SEQ*256;     // [128][512]
constexpr size_t O_DT = O_U  + (size_t)SEQ*512;     // [128][512]
constexpr size_t O_ZS = O_DT + (size_t)SEQ*512;     // [128][512] silu(z)
constexpr size_t O_BC = O_ZS + (size_t)SEQ*512;     // [128][32]
constexpr size_t O_YG = O_BC + (size_t)SEQ*32;      // [128][512]
constexpr size_t O_AH = O_YG + (size_t)SEQ*512;     // [128][256]

__device__ __forceinline__ float wsum(float p) {
    #pragma unroll
    for (int m = 1; m < 64; m <<= 1) p += __shfl_xor(p, m);
    return p;
}
__device__ __forceinline__ float dot4(float4 a, float4 b) {
    return a.x*b.x + a.y*b.y + a.z*b.z + a.w*b.w;
}

// ---------------- LDS-staged mini-GEMM ----------------
// dest[r][c] = sum_k A[r][k] * Wg[c*KK + k]  (+ addsrc[r][c]) (+ bias[c]),  c = 0..255.
// Weights streamed coalesced (8 dwordx4 in flight per thread per k-chunk); FMA from LDS.
// sW must be 256*36 floats. Caller syncs after the call before reading dest / reusing sW.
template<int MR, int KK>
__device__ __forceinline__ void gemm256(
    const float* __restrict__ Wg, const float* __restrict__ A, int AS,
    float* __restrict__ sW, float* __restrict__ dest, int DS,
    const float* __restrict__ addsrc, int ASS, const float* __restrict__ bias)
{
    const int tid = threadIdx.x;
    const int cs = tid >> 2, t = tid & 3;   // staging: col cs+64i, k-range t*8..t*8+7
    const int cg = cs, kq = t;              // compute: cols 4cg..4cg+3, k-quarter kq
    float acc[MR][4];
    #pragma unroll
    for (int r = 0; r < MR; ++r)
        #pragma unroll
        for (int j = 0; j < 4; ++j) acc[r][j] = 0.0f;

    for (int kc = 0; kc < KK; kc += 32) {
        __syncthreads();
        #pragma unroll
        for (int i = 0; i < 4; ++i) {
            const float* src = Wg + (size_t)(cs + 64*i)*KK + kc + t*8;
            float4 w0 = *(const float4*)src;
            float4 w1 = *(const float4*)(src + 4);
            float* dstp = &sW[(cs + 64*i)*36 + t*8];
            *(float4*)dstp       = w0;
            *(float4*)(dstp + 4) = w1;
        }
        __syncthreads();
        #pragma unroll
        for (int k4 = 0; k4 < 2; ++k4) {
            const int ko = kq*8 + k4*4;
            const int k  = kc + ko;
            float4 av[MR];
            #pragma unroll
            for (int r = 0; r < MR; ++r) av[r] = *(const float4*)&A[r*AS + k];
            #pragma unroll
            for (int j = 0; j < 4; ++j) {
                float4 wv = *(const float4*)&sW[(4*cg + j)*36 + ko];
                #pragma unroll
                for (int r = 0; r < MR; ++r)
                    acc[r][j] += av[r].x*wv.x + av[r].y*wv.y + av[r].z*wv.z + av[r].w*wv.w;
            }
        }
    }
    #pragma unroll
    for (int r = 0; r < MR; ++r)
        #pragma unroll
        for (int j = 0; j < 4; ++j) {
            float v = acc[r][j];
            v += __shfl_xor(v, 1);
            v += __shfl_xor(v, 2);
            acc[r][j] = v;
        }
    if (kq == 0) {
        #pragma unroll
        for (int r = 0; r < MR; ++r)
            #pragma unroll
            for (int j = 0; j < 4; ++j) {
                int c = 4*cg + j;
                float v = acc[r][j];
                if (bias)   v += bias[c];
                if (addsrc) v += addsrc[r*ASS + c];
                dest[r*DS + c] = v;
            }
    }
}

// LayerNorm of 4 rows (wave per row): dst = (src-mean)*rstd*w + b
__device__ __forceinline__ void ln4(const float* __restrict__ src, int SS,
                                    float* __restrict__ dst, int DS,
                                    const float* __restrict__ w, const float* __restrict__ b)
{
    int lane = threadIdx.x & 63, wv = threadIdx.x >> 6;
    const float* s = src + wv*SS;
    float4 x = *(const float4*)&s[lane*4];
    float sm = wsum(x.x + x.y + x.z + x.w);
    float mean = sm * (1.0f/256.0f);
    float dx0 = x.x-mean, dx1 = x.y-mean, dx2 = x.z-mean, dx3 = x.w-mean;
    float var = wsum(dx0*dx0 + dx1*dx1 + dx2*dx2 + dx3*dx3) * (1.0f/256.0f);
    float rstd = rsqrtf(var + 1e-5f);
    float4 ww = *(const float4*)&w[lane*4];
    float4 bb = *(const float4*)&b[lane*4];
    float4 o;
    o.x = dx0*rstd*ww.x + bb.x;
    o.y = dx1*rstd*ww.y + bb.y;
    o.z = dx2*rstd*ww.z + bb.z;
    o.w = dx3*rstd*ww.w + bb.w;
    *(float4*)&(dst + wv*DS)[lane*4] = o;
}

// ---------------- rowk: per-row fused layer-boundary kernel ----------------
// Block r: rebuild h rows r-3..r (KC of layer li-1, redundantly), write h[r];
// then KA of layer li: LN1 + in_proj(4 rows u-half + z row r) + conv + silu + x_proj + dt_proj.
__global__ __launch_bounds__(256) void rowk_kernel(
    const int* __restrict__ x, const float* __restrict__ emb,
    const float* __restrict__ n1w_l, const float* __restrict__ n1b_l,
    const float* __restrict__ n2w_l, const float* __restrict__ n2b_l,
    const float* __restrict__ ipw_l, const float* __restrict__ cw_l, const float* __restrict__ cb_l,
    const float* __restrict__ xpw_l, const float* __restrict__ dpw_l, const float* __restrict__ dpb_l,
    const float* __restrict__ opw_l, const float* __restrict__ aivw_l, const float* __restrict__ aivb_l,
    const float* __restrict__ aow_l, const float* __restrict__ aob_l,
    const float* __restrict__ nfw, const float* __restrict__ nfb,
    const float* __restrict__ hin, float* __restrict__ hout,
    const float* __restrict__ ygv, float* __restrict__ uv, float* __restrict__ dtv,
    float* __restrict__ zsv, float* __restrict__ bcv, float* __restrict__ AH,
    int li)
{
    __shared__ float SM[15552];                 // 60.75 KB
    float* hP  = SM;                            // [4][264] h_prev rows
    float* h1  = SM + 1056;                     // [4][264] h_cur rows
    float* sLN = SM + 2112;                     // [4][264]
    float* sAX = SM + 3168;                     // [4][520] yg / v / xraw-u
    float* zR  = SM + 5248;                     // [512]
    float* suR = SM + 5760;                     // [512]
    float* sxR = SM + 6272;                     // [64]
    float* sW  = SM + 6336;                     // [256][36]

    const int r = blockIdx.x;
    const int tid = threadIdx.x;
    const int lane = tid & 63, wv = tid >> 6;
    int rr[4];
    #pragma unroll
    for (int j = 0; j < 4; ++j) { int v = r - 3 + j; rr[j] = v < 0 ? 0 : v; }

    // ---- h_prev rows r-3..r ----
    if (li <= 1) {
        #pragma unroll
        for (int j = 0; j < 4; ++j)
            hP[j*264 + tid] = emb[(size_t)x[rr[j]]*256 + tid];
    } else {
        #pragma unroll
        for (int j = 0; j < 4; ++j)
            hP[j*264 + tid] = hin[rr[j]*256 + tid];
    }
    __syncthreads();

    float* hC = hP;
    if (li >= 1) {
        // ---- KC (layer li-1): out_proj + resid ; LN2 ; v ; attn_out + resid ----
        #pragma unroll
        for (int j = 0; j < 4; ++j) {
            sAX[j*520 + tid]       = ygv[rr[j]*512 + tid];
            sAX[j*520 + 256 + tid] = ygv[rr[j]*512 + 256 + tid];
        }
        __syncthreads();
        gemm256<4,512>(opw_l, sAX, 520, sW, h1, 264, hP, 264, nullptr);   // h1 = hP + out_proj(yg)
        __syncthreads();
        ln4(h1, 264, sLN, 264, n2w_l, n2b_l);
        __syncthreads();
        gemm256<4,256>(aivw_l, sLN, 264, sW, sAX, 520, nullptr, 0, aivb_l); // v
        __syncthreads();
        gemm256<4,256>(aow_l, sAX, 520, sW, h1, 264, h1, 264, aob_l);       // h1 += ao(v)+b
        __syncthreads();
        hC = h1;
        hout[r*256 + tid] = hC[3*264 + tid];
        if (li == 6) {
            // final LN of row r -> AH
            float v = hC[3*264 + tid];
            float s = wsum(v);
            float q = wsum(v*v);
            if (lane == 0) { sxR[wv] = s; sxR[4 + wv] = q; }
            __syncthreads();
            float mean = (sxR[0]+sxR[1]+sxR[2]+sxR[3]) * (1.0f/256.0f);
            float var  = (sxR[4]+sxR[5]+sxR[6]+sxR[7]) * (1.0f/256.0f) - mean*mean;
            float rstd = rsqrtf(var + 1e-5f);
            AH[r*256 + tid] = (v - mean)*rstd*nfw[tid] + nfb[tid];
            return;
        }
    }

    // ---- KA (layer li) ----
    ln4(hC, 264, sLN, 264, n1w_l, n1b_l);
    __syncthreads();
    // in_proj u-half (rows r-3..r), 512 cols in two chunks
    gemm256<4,256>(ipw_l,                     sLN, 264, sW, sAX,       520, nullptr, 0, nullptr);
    __syncthreads();
    gemm256<4,256>(ipw_l + (size_t)256*256,   sLN, 264, sW, sAX + 256, 520, nullptr, 0, nullptr);
    __syncthreads();
    // in_proj z-half (row r only)
    gemm256<1,256>(ipw_l + (size_t)512*256,   sLN + 3*264, 264, sW, zR,       512, nullptr, 0, nullptr);
    __syncthreads();
    gemm256<1,256>(ipw_l + (size_t)768*256,   sLN + 3*264, 264, sW, zR + 256, 512, nullptr, 0, nullptr);
    __syncthreads();

    // conv + bias + silu -> suR, u[r] ; zs[r] = silu(z)
    #pragma unroll
    for (int half = 0; half < 2; ++half) {
        int d = half*256 + tid;
        float4 c4 = *(const float4*)&cw_l[d*4];
        float acc = cb_l[d];
        if (r >= 3) acc += sAX[d]*c4.x;
        if (r >= 2) acc += sAX[520 + d]*c4.y;
        if (r >= 1) acc += sAX[1040 + d]*c4.z;
        acc += sAX[1560 + d]*c4.w;
        float sg = acc / (1.0f + __expf(-acc));
        suR[d] = sg;
        uv[r*512 + d] = sg;
        float z = zR[d];
        zsv[r*512 + d] = z / (1.0f + __expf(-z));
    }
    __syncthreads();

    // x_proj (48 cols, K=512): 4 waves x 12 cols, batched 4
    {
        float4 a0 = *(const float4*)&suR[lane*4];
        float4 a1 = *(const float4*)&suR[256 + lane*4];
        #pragma unroll
        for (int ci = 0; ci < 12; ci += 4) {
            float p[4];
            #pragma unroll
            for (int j = 0; j < 4; ++j) {
                int c = wv*12 + ci + j;
                float4 q0 = *(const float4*)&xpw_l[(size_t)c*512 + lane*4];
                float4 q1 = *(const float4*)&xpw_l[(size_t)c*512 + 256 + lane*4];
                p[j] = dot4(a0, q0) + dot4(a1, q1);
            }
            #pragma unroll
            for (int m = 1; m < 64; m <<= 1) {
                #pragma unroll
                for (int j = 0; j < 4; ++j) p[j] += __shfl_xor(p[j], m);
            }
            if (lane == 0) {
                #pragma unroll
                for (int j = 0; j < 4; ++j) sxR[wv*12 + ci + j] = p[j];
            }
        }
    }
    __syncthreads();
    if (tid >= 16 && tid < 48) bcv[r*32 + tid - 16] = sxR[tid];

    // dt_proj + bias + softplus
    {
        float4 sx0 = *(const float4*)&sxR[0];
        float4 sx1 = *(const float4*)&sxR[4];
        float4 sx2 = *(const float4*)&sxR[8];
        float4 sx3 = *(const float4*)&sxR[12];
        #pragma unroll
        for (int half = 0; half < 2; ++half) {
            int d = half*256 + tid;
            const float4* dp = (const float4*)&dpw_l[(size_t)d*16];
            float acc = dpb_l[d] + dot4(dp[0], sx0) + dot4(dp[1], sx1)
                                 + dot4(dp[2], sx2) + dot4(dp[3], sx3);
            dtv[r*512 + d] = fmaxf(acc, 0.0f) + log1pf(__expf(-fabsf(acc)));
        }
    }
}

// ---------------- selective scan + skip + gate (verified structure) ----------------
__global__ __launch_bounds__(256) void scan_kernel(
    const float* __restrict__ dt, const float* __restrict__ u, const float* __restrict__ zs,
    const float* __restrict__ bcv,
    const float* __restrict__ alog_l, const float* __restrict__ dsk_l,
    float* __restrict__ yg)
{
    __shared__ float s5[5*128];
    float* sdt = s5;        float* su2 = s5 + 128;
    float* sz2 = s5 + 256;  float* sB  = s5 + 384;  float* sC = s5 + 512;
    int tid = threadIdx.x;
    int s  = tid & 15, dl = tid >> 4;
    int d0 = blockIdx.x * 16;
    int d  = d0 + dl;
    float a_ds = -__expf(alog_l[d*16 + s]);
    float dskv = dsk_l[d];
    float hst = 0.0f;
    for (int t0 = 0; t0 < SEQ; t0 += 8) {
        __syncthreads();
        if (tid < 128) {
            int tt = tid >> 4, j = tid & 15;
            int t = t0 + tt;
            sdt[tt*16+j] = dt[t*512 + d0 + j];
            su2[tt*16+j] = u [t*512 + d0 + j];
            sz2[tt*16+j] = zs[t*512 + d0 + j];
        } else {
            int q = tid - 128;
            int tt = q >> 4, j = q & 15;
            int t = t0 + tt;
            sB[tt*16+j] = bcv[t*32 + j];
            sC[tt*16+j] = bcv[t*32 + 16 + j];
        }
        __syncthreads();
        #pragma unroll
        for (int tt = 0; tt < 8; ++tt) {
            float dtvv = sdt[tt*16+dl];
            float uvv  = su2[tt*16+dl];
            hst = __expf(dtvv * a_ds) * hst + dtvv * uvv * sB[tt*16+s];
            float p = hst * sC[tt*16+s];
            p += __shfl_xor(p, 1);
            p += __shfl_xor(p, 2);
            p += __shfl_xor(p, 4);
            p += __shfl_xor(p, 8);
            if (s == 0) {
                float y = p + uvv * dskv;
                yg[(t0+tt)*512 + d] = y * sz2[tt*16+dl];
            }
        }
    }
}

// ---------------- head GEMM: out(128,32000) = AH @ emb^T + hb ; pad-129 LDS ----------------
__global__ __launch_bounds__(256) void head_kernel(
    const float* __restrict__ AH, const float* __restrict__ emb,
    const float* __restrict__ hb, float* __restrict__ out)
{
    __shared__ float sA[32*129];
    __shared__ float sW[32*129];
    int tid = threadIdx.x;
    int c0 = blockIdx.x * 128;
    int rr = tid >> 1;
    int kj = (tid & 1) * 16;
    int r4 = (tid >> 4) * 4;
    int c4 = (tid & 15) * 4;
    float acc[8][8] = {};

    for (int kc = 0; kc < 256; kc += 32) {
        __syncthreads();
        #pragma unroll
        for (int i = 0; i < 4; ++i) {
            float4 a = *(const float4*)&AH[(size_t)rr*256 + kc + kj + i*4];
            sA[(kj+i*4+0)*129 + rr] = a.x;
            sA[(kj+i*4+1)*129 + rr] = a.y;
            sA[(kj+i*4+2)*129 + rr] = a.z;
            sA[(kj+i*4+3)*129 + rr] = a.w;
            float4 w = *(const float4*)&emb[(size_t)(c0+rr)*256 + kc + kj + i*4];
            sW[(kj+i*4+0)*129 + rr] = w.x;
            sW[(kj+i*4+1)*129 + rr] = w.y;
            sW[(kj+i*4+2)*129 + rr] = w.z;
            sW[(kj+i*4+3)*129 + rr] = w.w;
        }
        __syncthreads();
        #pragma unroll
        for (int k = 0; k < 32; ++k) {
            float4 a0 = *(const float4*)&sA[k*129 + r4];
            float4 a1 = *(const float4*)&sA[k*129 + 64 + r4];
            float4 b0 = *(const float4*)&sW[k*129 + c4];
            float4 b1 = *(const float4*)&sW[k*129 + 64 + c4];
            float av[8] = {a0.x,a0.y,a0.z,a0.w, a1.x,a1.y,a1.z,a1.w};
            float bv[8] = {b0.x,b0.y,b0.z,b0.w, b1.x,b1.y,b1.z,b1.w};
            #pragma unroll
            for (int i = 0; i < 8; ++i)
                #pragma unroll
                for (int j = 0; j < 8; ++j)
                    acc[i][j] += av[i]*bv[j];
        }
    }
    #pragma unroll
    for (int i = 0; i < 8; ++i) {
        int r = (i < 4) ? (r4 + i) : (64 + r4 + i - 4);
        #pragma unroll
        for (int jh = 0; jh < 2; ++jh) {
            int c = c0 + jh*64 + c4;
            float4 h4 = *(const float4*)&hb[c];
            float4 o;
            o.x = acc[i][jh*4+0] + h4.x;
            o.y = acc[i][jh*4+1] + h4.y;
            o.z = acc[i][jh*4+2] + h4.z;
            o.w = acc[i][jh*4+3] + h4.w;
            *(float4*)&out[(size_t)r*NVOCAB + c] = o;
        }
    }
}

// ---------------- launch (14 nodes) ----------------
extern "C" void kernel_launch(void* const* d_in, const int* in_sizes, int n_in,
                              void* d_out, int out_size, void* d_ws, size_t ws_size,
                              hipStream_t stream)
{
    const int*   xin = (const int*)d_in[0];
    const float* emb = (const float*)d_in[1];
    const float* n1w = (const float*)d_in[2];
    const float* n1b = (const float*)d_in[3];
    const float* n2w = (const float*)d_in[4];
    const float* n2b = (const float*)d_in[5];
    const float* ipw = (const float*)d_in[6];
    const float* cw  = (const float*)d_in[7];
    const float* cb  = (const float*)d_in[8];
    const float* xpw = (const float*)d_in[9];
    const float* dpw = (const float*)d_in[10];
    const float* dpb = (const float*)d_in[11];
    const float* alog= (const float*)d_in[12];
    const float* dsk = (const float*)d_in[13];
    const float* opw = (const float*)d_in[14];
    const float* aiw = (const float*)d_in[15];
    const float* aib = (const float*)d_in[16];
    const float* aow = (const float*)d_in[17];
    const float* aob = (const float*)d_in[18];
    const float* nfw = (const float*)d_in[19];
    const float* nfb = (const float*)d_in[20];
    const float* hb  = (const float*)d_in[21];
    float* ws  = (float*)d_ws;
    float* out = (float*)d_out;

    for (int i = 0; i <= 6; ++i) {
        int ka = i <= 5 ? i : 5;          // KA layer (unused when i==6)
        int kc = i >= 1 ? i - 1 : 0;      // KC layer (unused when i==0)
        const float* hin  = (i % 2 == 0) ? ws + O_HA : ws + O_HB;
        float*       hout = (i % 2 == 0) ? ws + O_HB : ws + O_HA;
        rowk_kernel<<<128, 256, 0, stream>>>(
            xin, emb,
            n1w + ka*256, n1b + ka*256,
            n2w + kc*256, n2b + kc*256,
            ipw + (size_t)ka*1024*256, cw + (size_t)ka*512*4, cb + ka*512,
            xpw + (size_t)ka*48*512, dpw + (size_t)ka*512*16, dpb + ka*512,
            opw + (size_t)kc*256*512,
            aiw + (size_t)kc*768*256 + (size_t)512*256, aib + kc*768 + 512,
            aow + (size_t)kc*256*256, aob + kc*256,
            nfw, nfb,
            hin, hout,
            ws + O_YG, ws + O_U, ws + O_DT, ws + O_ZS, ws + O_BC, ws + O_AH,
            i);
        if (i <= 5)
            scan_kernel<<<32, 256, 0, stream>>>(
                ws + O_DT, ws + O_U, ws + O_ZS, ws + O_BC,
                alog + (size_t)i*512*16, dsk + i*512, ws + O_YG);
    }
    head_kernel<<<NVOCAB/128, 256, 0, stream>>>(ws + O_AH, emb, hb, out);
}

// Round 8
// 582.081 us; speedup vs baseline: 3.2276x; 1.4099x over previous
//
#include <hip/hip_runtime.h>

constexpr int SEQ    = 128;
constexpr int NVOCAB = 32000;

// ---------------- workspace layout (float offsets) ----------------
constexpr size_t O_HA = 0;                          // [128][256]
constexpr size_t O_HB = O_HA + (size_t)SEQ*256;     // [128][256]
constexpr size_t O_U  = O_HB + (size_t)SEQ*256;     // [128][512]
constexpr size_t O_DT = O_U  + (size_t)SEQ*512;     // [128][512]
constexpr size_t O_ZS = O_DT + (size_t)SEQ*512;     // [128][512] silu(z)
constexpr size_t O_BC = O_ZS + (size_t)SEQ*512;     // [128][32]
constexpr size_t O_YG = O_BC + (size_t)SEQ*32;      // [128][512]
constexpr size_t O_AH = O_YG + (size_t)SEQ*512;     // [128][256]

__device__ __forceinline__ float wsum(float p) {
    #pragma unroll
    for (int m = 1; m < 64; m <<= 1) p += __shfl_xor(p, m);
    return p;
}
__device__ __forceinline__ float dot4(float4 a, float4 b) {
    return a.x*b.x + a.y*b.y + a.z*b.z + a.w*b.w;
}

// ---------------- register-W mini-GEMM, 16 waves, static double-buffer ----------------
// dest[r][c] = sum_k A[r][k]*Wg[c*KK+k] (+addsrc[r][c]) (+bias[c]), c=0..255.
// Wave wv owns cols wv*16..wv*16+15; lane (cs,tq) owns col wv*16+cs, k-slice tq*8..+7
// of each 32-chunk. W global->register, explicit even/odd buffers (no runtime index).
// A: LDS broadcast float4 reads. 2-level shuffle reduce over tq at the end.
// No internal __syncthreads; caller syncs before reading dest.
template<int MR, int KK>
__device__ __forceinline__ void gemmX(
    const float* __restrict__ Wg, const float* __restrict__ A, int AS,
    float* __restrict__ dest, int DS,
    const float* __restrict__ addsrc, int ASS, const float* __restrict__ bias)
{
    const int lane = threadIdx.x & 63;
    const int wv   = threadIdx.x >> 6;       // 0..15
    const int tq = lane & 3, cs = lane >> 2; // k-quarter, col-in-wave
    const int c  = wv*16 + cs;               // 0..255
    const float* Wp = Wg + (size_t)c*KK + tq*8;
    float acc[MR];
    #pragma unroll
    for (int r = 0; r < MR; ++r) acc[r] = 0.0f;

    float4 w0a = *(const float4*)(Wp);
    float4 w0b = *(const float4*)(Wp + 4);
    float4 w1a, w1b;
    #pragma unroll
    for (int kc = 0; kc < KK; kc += 64) {
        if (kc + 32 < KK) {
            w1a = *(const float4*)(Wp + kc + 32);
            w1b = *(const float4*)(Wp + kc + 36);
        }
        #pragma unroll
        for (int r = 0; r < MR; ++r) {
            float4 a0 = *(const float4*)&A[r*AS + kc + tq*8];
            float4 a1 = *(const float4*)&A[r*AS + kc + tq*8 + 4];
            acc[r] += dot4(a0, w0a) + dot4(a1, w0b);
        }
        if (kc + 64 < KK) {
            w0a = *(const float4*)(Wp + kc + 64);
            w0b = *(const float4*)(Wp + kc + 68);
        }
        if (kc + 32 < KK) {
            #pragma unroll
            for (int r = 0; r < MR; ++r) {
                float4 a0 = *(const float4*)&A[r*AS + kc + 32 + tq*8];
                float4 a1 = *(const float4*)&A[r*AS + kc + 36 + tq*8];
                acc[r] += dot4(a0, w1a) + dot4(a1, w1b);
            }
        }
    }
    #pragma unroll
    for (int r = 0; r < MR; ++r) {
        float v = acc[r];
        v += __shfl_xor(v, 1);
        v += __shfl_xor(v, 2);
        acc[r] = v;
    }
    if (tq == 0) {
        #pragma unroll
        for (int r = 0; r < MR; ++r) {
            float v = acc[r];
            if (bias)   v += bias[c];
            if (addsrc) v += addsrc[r*ASS + c];
            dest[r*DS + c] = v;
        }
    }
}

// LayerNorm of one 256-float row by one wave: dst = (src-mean)*rstd*w + b
__device__ __forceinline__ void ln_row(const float* __restrict__ src, float* __restrict__ dst,
                                       const float* __restrict__ w, const float* __restrict__ b)
{
    int lane = threadIdx.x & 63;
    float4 x = *(const float4*)&src[lane*4];
    float sm = wsum(x.x + x.y + x.z + x.w);
    float mean = sm * (1.0f/256.0f);
    float d0 = x.x-mean, d1 = x.y-mean, d2 = x.z-mean, d3 = x.w-mean;
    float var = wsum(d0*d0 + d1*d1 + d2*d2 + d3*d3) * (1.0f/256.0f);
    float rstd = rsqrtf(var + 1e-5f);
    float4 ww = *(const float4*)&w[lane*4];
    float4 bb = *(const float4*)&b[lane*4];
    float4 o;
    o.x = d0*rstd*ww.x + bb.x;
    o.y = d1*rstd*ww.y + bb.y;
    o.z = d2*rstd*ww.z + bb.z;
    o.w = d3*rstd*ww.w + bb.w;
    *(float4*)&dst[lane*4] = o;
}

// ---------------- rowk: per-row fused layer-boundary kernel (1024 threads) ----------------
// Block r: rebuild h rows r-3..r (KC of layer li-1, redundantly), write h[r];
// then KA of layer li: LN1 + in_proj + conv + silu + x_proj + dt_proj.
__global__ __launch_bounds__(1024) void rowk_kernel(
    const int* __restrict__ x, const float* __restrict__ emb,
    const float* __restrict__ n1w_l, const float* __restrict__ n1b_l,
    const float* __restrict__ n2w_l, const float* __restrict__ n2b_l,
    const float* __restrict__ ipw_l, const float* __restrict__ cw_l, const float* __restrict__ cb_l,
    const float* __restrict__ xpw_l, const float* __restrict__ dpw_l, const float* __restrict__ dpb_l,
    const float* __restrict__ opw_l, const float* __restrict__ aivw_l, const float* __restrict__ aivb_l,
    const float* __restrict__ aow_l, const float* __restrict__ aob_l,
    const float* __restrict__ nfw, const float* __restrict__ nfb,
    const float* __restrict__ hin, float* __restrict__ hout,
    const float* __restrict__ ygv, float* __restrict__ uv, float* __restrict__ dtv,
    float* __restrict__ zsv, float* __restrict__ bcv, float* __restrict__ AH,
    int li)
{
    __shared__ float SM[6336];                  // 24.75 KB
    float* hP  = SM;                            // [4][264] h_prev rows
    float* h1  = SM + 1056;                     // [4][264] h_cur rows
    float* sLN = SM + 2112;                     // [4][264]
    float* sAX = SM + 3168;                     // [4][520] yg / v / u-raw
    float* zR  = SM + 5248;                     // [512]
    float* suR = SM + 5760;                     // [512]
    float* sxR = SM + 6272;                     // [64]

    const int r = blockIdx.x;
    const int tid = threadIdx.x;
    const int lane = tid & 63, wv = tid >> 6;
    int rr[4];
    #pragma unroll
    for (int j = 0; j < 4; ++j) { int v = r - 3 + j; rr[j] = v < 0 ? 0 : v; }

    // ---- h_prev rows r-3..r (one write per thread) ----
    {
        int hr = tid >> 8, hc = tid & 255;
        if (li <= 1) hP[hr*264 + hc] = emb[(size_t)x[rr[hr]]*256 + hc];
        else         hP[hr*264 + hc] = hin[rr[hr]*256 + hc];
    }
    __syncthreads();

    float* hC = hP;
    if (li >= 1) {
        // ---- KC (layer li-1): out_proj + resid ; LN2 ; v ; attn_out + resid ----
        {
            int yr = tid >> 9, yc = tid & 511;
            sAX[yr*520 + yc]     = ygv[rr[yr]*512 + yc];
            sAX[(2+yr)*520 + yc] = ygv[rr[2+yr]*512 + yc];
        }
        __syncthreads();
        gemmX<4,512>(opw_l, sAX, 520, h1, 264, hP, 264, nullptr);    // h1 = hP + out_proj(yg)
        __syncthreads();
        if (wv < 4) ln_row(h1 + wv*264, sLN + wv*264, n2w_l, n2b_l);
        __syncthreads();
        gemmX<4,256>(aivw_l, sLN, 264, sAX, 520, nullptr, 0, aivb_l); // v
        __syncthreads();
        gemmX<4,256>(aow_l, sAX, 520, h1, 264, h1, 264, aob_l);       // h1 += ao(v)+b
        __syncthreads();
        hC = h1;
        if (tid < 256) hout[r*256 + tid] = h1[3*264 + tid];
        if (li == 6) {
            if (tid < 256) {
                float v = h1[3*264 + tid];
                float s = wsum(v);
                float q = wsum(v*v);
                if (lane == 0) { sxR[wv] = s; sxR[8 + wv] = q; }
            }
            __syncthreads();
            if (tid < 256) {
                float v = h1[3*264 + tid];
                float mean = (sxR[0]+sxR[1]+sxR[2]+sxR[3]) * (1.0f/256.0f);
                float var  = (sxR[8]+sxR[9]+sxR[10]+sxR[11]) * (1.0f/256.0f) - mean*mean;
                float rstd = rsqrtf(var + 1e-5f);
                AH[r*256 + tid] = (v - mean)*rstd*nfw[tid] + nfb[tid];
            }
            return;
        }
    }

    // ---- KA (layer li) ----
    if (wv < 4) ln_row(hC + wv*264, sLN + wv*264, n1w_l, n1b_l);
    __syncthreads();
    gemmX<4,256>(ipw_l,                   sLN, 264, sAX,       520, nullptr, 0, nullptr);
    __syncthreads();
    gemmX<4,256>(ipw_l + (size_t)256*256, sLN, 264, sAX + 256, 520, nullptr, 0, nullptr);
    __syncthreads();
    gemmX<1,256>(ipw_l + (size_t)512*256, sLN + 3*264, 264, zR,       512, nullptr, 0, nullptr);
    __syncthreads();
    gemmX<1,256>(ipw_l + (size_t)768*256, sLN + 3*264, 264, zR + 256, 512, nullptr, 0, nullptr);
    __syncthreads();

    // conv + bias + silu -> suR, u[r] ; zs[r] = silu(z)
    if (tid < 512) {
        int d = tid;
        float4 c4 = *(const float4*)&cw_l[d*4];
        float acc = cb_l[d];
        if (r >= 3) acc += sAX[d]        * c4.x;
        if (r >= 2) acc += sAX[520 + d]  * c4.y;
        if (r >= 1) acc += sAX[1040 + d] * c4.z;
        acc += sAX[1560 + d] * c4.w;
        float sg = acc / (1.0f + __expf(-acc));
        suR[d] = sg;
        uv[r*512 + d] = sg;
        float z = zR[d];
        zsv[r*512 + d] = z / (1.0f + __expf(-z));
    }
    __syncthreads();

    // x_proj (48 cols, K=512): 16 waves x 3 cols
    {
        float4 a0 = *(const float4*)&suR[lane*4];
        float4 a1 = *(const float4*)&suR[256 + lane*4];
        float p[3];
        #pragma unroll
        for (int j = 0; j < 3; ++j) {
            int c = wv*3 + j;
            float4 q0 = *(const float4*)&xpw_l[(size_t)c*512 + lane*4];
            float4 q1 = *(const float4*)&xpw_l[(size_t)c*512 + 256 + lane*4];
            p[j] = dot4(a0, q0) + dot4(a1, q1);
        }
        #pragma unroll
        for (int m = 1; m < 64; m <<= 1) {
            #pragma unroll
            for (int j = 0; j < 3; ++j) p[j] += __shfl_xor(p[j], m);
        }
        if (lane == 0) {
            #pragma unroll
            for (int j = 0; j < 3; ++j) sxR[wv*3 + j] = p[j];
        }
    }
    __syncthreads();
    if (tid >= 16 && tid < 48) bcv[r*32 + tid - 16] = sxR[tid];

    // dt_proj + bias + softplus
    if (tid < 512) {
        int d = tid;
        float4 sx0 = *(const float4*)&sxR[0];
        float4 sx1 = *(const float4*)&sxR[4];
        float4 sx2 = *(const float4*)&sxR[8];
        float4 sx3 = *(const float4*)&sxR[12];
        const float4* dp = (const float4*)&dpw_l[(size_t)d*16];
        float acc = dpb_l[d] + dot4(dp[0], sx0) + dot4(dp[1], sx1)
                             + dot4(dp[2], sx2) + dot4(dp[3], sx3);
        dtv[r*512 + d] = fmaxf(acc, 0.0f) + log1pf(__expf(-fabsf(acc)));
    }
}

// ---------------- selective scan + skip + gate (verified structure) ----------------
__global__ __launch_bounds__(256) void scan_kernel(
    const float* __restrict__ dt, const float* __restrict__ u, const float* __restrict__ zs,
    const float* __restrict__ bcv,
    const float* __restrict__ alog_l, const float* __restrict__ dsk_l,
    float* __restrict__ yg)
{
    __shared__ float s5[5*128];
    float* sdt = s5;        float* su2 = s5 + 128;
    float* sz2 = s5 + 256;  float* sB  = s5 + 384;  float* sC = s5 + 512;
    int tid = threadIdx.x;
    int s  = tid & 15, dl = tid >> 4;
    int d0 = blockIdx.x * 16;
    int d  = d0 + dl;
    float a_ds = -__expf(alog_l[d*16 + s]);
    float dskv = dsk_l[d];
    float hst = 0.0f;
    for (int t0 = 0; t0 < SEQ; t0 += 8) {
        __syncthreads();
        if (tid < 128) {
            int tt = tid >> 4, j = tid & 15;
            int t = t0 + tt;
            sdt[tt*16+j] = dt[t*512 + d0 + j];
            su2[tt*16+j] = u [t*512 + d0 + j];
            sz2[tt*16+j] = zs[t*512 + d0 + j];
        } else {
            int q = tid - 128;
            int tt = q >> 4, j = q & 15;
            int t = t0 + tt;
            sB[tt*16+j] = bcv[t*32 + j];
            sC[tt*16+j] = bcv[t*32 + 16 + j];
        }
        __syncthreads();
        #pragma unroll
        for (int tt = 0; tt < 8; ++tt) {
            float dtvv = sdt[tt*16+dl];
            float uvv  = su2[tt*16+dl];
            hst = __expf(dtvv * a_ds) * hst + dtvv * uvv * sB[tt*16+s];
            float p = hst * sC[tt*16+s];
            p += __shfl_xor(p, 1);
            p += __shfl_xor(p, 2);
            p += __shfl_xor(p, 4);
            p += __shfl_xor(p, 8);
            if (s == 0) {
                float y = p + uvv * dskv;
                yg[(t0+tt)*512 + d] = y * sz2[tt*16+dl];
            }
        }
    }
}

// ---------------- head GEMM: out(128,32000) = AH @ emb^T + hb ; pad-129 LDS ----------------
__global__ __launch_bounds__(256) void head_kernel(
    const float* __restrict__ AH, const float* __restrict__ emb,
    const float* __restrict__ hb, float* __restrict__ out)
{
    __shared__ float sA[32*129];
    __shared__ float sW[32*129];
    int tid = threadIdx.x;
    int c0 = blockIdx.x * 128;
    int rr = tid >> 1;
    int kj = (tid & 1) * 16;
    int r4 = (tid >> 4) * 4;
    int c4 = (tid & 15) * 4;
    float acc[8][8] = {};

    for (int kc = 0; kc < 256; kc += 32) {
        __syncthreads();
        #pragma unroll
        for (int i = 0; i < 4; ++i) {
            float4 a = *(const float4*)&AH[(size_t)rr*256 + kc + kj + i*4];
            sA[(kj+i*4+0)*129 + rr] = a.x;
            sA[(kj+i*4+1)*129 + rr] = a.y;
            sA[(kj+i*4+2)*129 + rr] = a.z;
            sA[(kj+i*4+3)*129 + rr] = a.w;
            float4 w = *(const float4*)&emb[(size_t)(c0+rr)*256 + kc + kj + i*4];
            sW[(kj+i*4+0)*129 + rr] = w.x;
            sW[(kj+i*4+1)*129 + rr] = w.y;
            sW[(kj+i*4+2)*129 + rr] = w.z;
            sW[(kj+i*4+3)*129 + rr] = w.w;
        }
        __syncthreads();
        #pragma unroll
        for (int k = 0; k < 32; ++k) {
            float4 a0 = *(const float4*)&sA[k*129 + r4];
            float4 a1 = *(const float4*)&sA[k*129 + 64 + r4];
            float4 b0 = *(const float4*)&sW[k*129 + c4];
            float4 b1 = *(const float4*)&sW[k*129 + 64 + c4];
            float av[8] = {a0.x,a0.y,a0.z,a0.w, a1.x,a1.y,a1.z,a1.w};
            float bv[8] = {b0.x,b0.y,b0.z,b0.w, b1.x,b1.y,b1.z,b1.w};
            #pragma unroll
            for (int i = 0; i < 8; ++i)
                #pragma unroll
                for (int j = 0; j < 8; ++j)
                    acc[i][j] += av[i]*bv[j];
        }
    }
    #pragma unroll
    for (int i = 0; i < 8; ++i) {
        int r = (i < 4) ? (r4 + i) : (64 + r4 + i - 4);
        #pragma unroll
        for (int jh = 0; jh < 2; ++jh) {
            int c = c0 + jh*64 + c4;
            float4 h4 = *(const float4*)&hb[c];
            float4 o;
            o.x = acc[i][jh*4+0] + h4.x;
            o.y = acc[i][jh*4+1] + h4.y;
            o.z = acc[i][jh*4+2] + h4.z;
            o.w = acc[i][jh*4+3] + h4.w;
            *(float4*)&out[(size_t)r*NVOCAB + c] = o;
        }
    }
}

// ---------------- launch (14 nodes) ----------------
extern "C" void kernel_launch(void* const* d_in, const int* in_sizes, int n_in,
                              void* d_out, int out_size, void* d_ws, size_t ws_size,
                              hipStream_t stream)
{
    const int*   xin = (const int*)d_in[0];
    const float* emb = (const float*)d_in[1];
    const float* n1w = (const float*)d_in[2];
    const float* n1b = (const float*)d_in[3];
    const float* n2w = (const float*)d_in[4];
    const float* n2b = (const float*)d_in[5];
    const float* ipw = (const float*)d_in[6];
    const float* cw  = (const float*)d_in[7];
    const float* cb  = (const float*)d_in[8];
    const float* xpw = (const float*)d_in[9];
    const float* dpw = (const float*)d_in[10];
    const float* dpb = (const float*)d_in[11];
    const float* alog= (const float*)d_in[12];
    const float* dsk = (const float*)d_in[13];
    const float* opw = (const float*)d_in[14];
    const float* aiw = (const float*)d_in[15];
    const float* aib = (const float*)d_in[16];
    const float* aow = (const float*)d_in[17];
    const float* aob = (const float*)d_in[18];
    const float* nfw = (const float*)d_in[19];
    const float* nfb = (const float*)d_in[20];
    const float* hb  = (const float*)d_in[21];
    float* ws  = (float*)d_ws;
    float* out = (float*)d_out;

    for (int i = 0; i <= 6; ++i) {
        int ka = i <= 5 ? i : 5;          // KA layer (unused when i==6)
        int kc = i >= 1 ? i - 1 : 0;      // KC layer (unused when i==0)
        const float* hin  = (i % 2 == 0) ? ws + O_HA : ws + O_HB;
        float*       hout = (i % 2 == 0) ? ws + O_HB : ws + O_HA;
        rowk_kernel<<<128, 1024, 0, stream>>>(
            xin, emb,
            n1w + ka*256, n1b + ka*256,
            n2w + kc*256, n2b + kc*256,
            ipw + (size_t)ka*1024*256, cw + (size_t)ka*512*4, cb + ka*512,
            xpw + (size_t)ka*48*512, dpw + (size_t)ka*512*16, dpb + ka*512,
            opw + (size_t)kc*256*512,
            aiw + (size_t)kc*768*256 + (size_t)512*256, aib + kc*768 + 512,
            aow + (size_t)kc*256*256, aob + kc*256,
            nfw, nfb,
            hin, hout,
            ws + O_YG, ws + O_U, ws + O_DT, ws + O_ZS, ws + O_BC, ws + O_AH,
            i);
        if (i <= 5)
            scan_kernel<<<32, 256, 0, stream>>>(
                ws + O_DT, ws + O_U, ws + O_ZS, ws + O_BC,
                alog + (size_t)i*512*16, dsk + i*512, ws + O_YG);
    }
    head_kernel<<<NVOCAB/128, 256, 0, stream>>>(ws + O_AH, emb, hb, out);
}